// Round 7
// baseline (791.733 us; speedup 1.0000x reference)
//
#include <hip/hip_runtime.h>
#include <hip/hip_bf16.h>

#define N_NODES 100000
#define M_PAD   100096   // 782 * 128 — GEMM A-buffers padded so frag loads never go OOB
#define SCAN_B  98       // ceil(N_NODES / 1024)

typedef __attribute__((ext_vector_type(8))) short s8v;   // 8 x bf16 (4 VGPR) MFMA operand
typedef __attribute__((ext_vector_type(4))) float f4v;   // MFMA accumulator
typedef unsigned short u16;
typedef unsigned int   u32;

__device__ __forceinline__ u16 f2bf(float v) {
    __hip_bfloat16 b = __float2bfloat16(v);
    return __builtin_bit_cast(u16, b);
}
__device__ __forceinline__ float bf2f(u16 u) {
    u32 t = (u32)u << 16;
    return __builtin_bit_cast(float, t);
}
__device__ __forceinline__ float bflo(u32 p) { return __builtin_bit_cast(float, p << 16); }
__device__ __forceinline__ float bfhi(u32 p) { return __builtin_bit_cast(float, p & 0xffff0000u); }

// ---------------------------------------------------------------------------
// Graph prep
// ---------------------------------------------------------------------------

__global__ __launch_bounds__(256) void k_zero_int(int* __restrict__ p, int n) {
    int i = blockIdx.x * 256 + threadIdx.x;
    if (i < n) p[i] = 0;
}

__global__ __launch_bounds__(256) void k_count(const int* __restrict__ ei, int E,
                                               int* __restrict__ cnt) {
    for (int e = blockIdx.x * 256 + threadIdx.x; e < E; e += gridDim.x * 256)
        atomicAdd(&cnt[ei[E + e]], 1);
}

// scan phase A: per-block exclusive scan (1024 elems/block) + block sums + dis
__global__ __launch_bounds__(1024) void k_scan_a(const int* __restrict__ cnt,
                                                 int* __restrict__ row_ptr,
                                                 int* __restrict__ bsum,
                                                 float* __restrict__ dis, int n) {
    __shared__ int wsum[16];
    const int tid = threadIdx.x;
    const int lane = tid & 63;
    const int wv = tid >> 6;
    const int i = blockIdx.x * 1024 + tid;
    const int v = (i < n) ? cnt[i] : 0;
    if (i < n) dis[i] = 1.0f / sqrtf((float)(v + 1));
    int x = v;
    #pragma unroll
    for (int d = 1; d < 64; d <<= 1) {
        int t = __shfl_up(x, d, 64);
        if (lane >= d) x += t;
    }
    if (lane == 63) wsum[wv] = x;
    __syncthreads();
    int woff = 0, total = 0;
    #pragma unroll
    for (int w = 0; w < 16; ++w) {
        int s = wsum[w];
        if (w < wv) woff += s;
        total += s;
    }
    if (i < n) row_ptr[i] = woff + x - v;  // block-local exclusive
    if (tid == 0) bsum[blockIdx.x] = total;
}

// scan phase B: exclusive scan of SCAN_B block sums (1 block, 128 thr)
__global__ __launch_bounds__(128) void k_scan_b(int* __restrict__ bsum,
                                                int* __restrict__ row_ptr,
                                                int nparts, int n, int total_edges) {
    __shared__ int w0tot;
    const int tid = threadIdx.x;
    const int lane = tid & 63;
    const int v = (tid < nparts) ? bsum[tid] : 0;
    int x = v;
    #pragma unroll
    for (int d = 1; d < 64; d <<= 1) {
        int t = __shfl_up(x, d, 64);
        if (lane >= d) x += t;
    }
    if (tid == 63) w0tot = x;
    __syncthreads();
    int excl = x - v + ((tid >= 64) ? w0tot : 0);
    if (tid < nparts) bsum[tid] = excl;
    if (tid == 0) row_ptr[n] = total_edges;
}

// scan phase C: add block offset, init cursor
__global__ __launch_bounds__(1024) void k_scan_c(int* __restrict__ row_ptr,
                                                 const int* __restrict__ bsum,
                                                 int* __restrict__ cursor, int n) {
    const int i = blockIdx.x * 1024 + threadIdx.x;
    if (i < n) {
        const int r = row_ptr[i] + bsum[blockIdx.x];
        row_ptr[i] = r;
        cursor[i] = r;
    }
}

// counting-sort scatter: edge -> slot in dst's CSR row; pack (src, norm) as int2
__global__ __launch_bounds__(256) void k_scatter(const int* __restrict__ ei, int E,
                                                 const float* __restrict__ dis,
                                                 int* __restrict__ cursor,
                                                 int2* __restrict__ edat) {
    for (int e = blockIdx.x * 256 + threadIdx.x; e < E; e += gridDim.x * 256) {
        const int s = ei[e];
        const int d = ei[E + e];
        const int pos = atomicAdd(&cursor[d], 1);
        edat[pos] = make_int2(s, __float_as_int(dis[s] * dis[d]));
    }
}

// ---------------------------------------------------------------------------
// Weight prep: W[K][N] fp32 -> transposed split Wt_hi/Wt_lo [N][K] bf16
// ---------------------------------------------------------------------------
__global__ __launch_bounds__(256) void k_prep_w(const float* __restrict__ W,
                                                u16* __restrict__ Wth,
                                                u16* __restrict__ Wtl,
                                                int K, int N) {
    const int n = blockIdx.x;
    for (int k = threadIdx.x; k < K; k += 256) {
        float v = W[(size_t)k * N + n];
        u16 hi = f2bf(v);
        Wth[(size_t)n * K + k] = hi;
        Wtl[(size_t)n * K + k] = f2bf(v - bf2f(hi));
    }
}

// x fp32 -> bf16 (8 elems/thread)
__global__ __launch_bounds__(256) void k_x2bf(const float* __restrict__ x,
                                              u16* __restrict__ xb, long n8) {
    long i = (long)blockIdx.x * 256 + threadIdx.x;
    if (i >= n8) return;
    const float4 a = *reinterpret_cast<const float4*>(x + i * 8);
    const float4 b = *reinterpret_cast<const float4*>(x + i * 8 + 4);
    uint4 p;
    p.x = (u32)f2bf(a.x) | ((u32)f2bf(a.y) << 16);
    p.y = (u32)f2bf(a.z) | ((u32)f2bf(a.w) << 16);
    p.z = (u32)f2bf(b.x) | ((u32)f2bf(b.y) << 16);
    p.w = (u32)f2bf(b.z) | ((u32)f2bf(b.w) << 16);
    *reinterpret_cast<uint4*>(xb + i * 8) = p;
}

// ---------------------------------------------------------------------------
// Streaming split-bf16 MFMA GEMM — NO LDS, NO barriers.
// Both operand fragments are loaded straight from global into registers:
//   operand a (n side, from Bt[N][K], L2-hot: <=256KB total)
//   operand b (m side, from A[M][K] pair, HBM-streamed; 2x reuse hits L2)
// Lane l loads 16B at row(l)*K + kg(l): 4 lanes cover 64 contiguous bytes
// of each row -> full cache lines. Swapped-operand epilogue (HW-validated
// round 4): row = row0+wm*64+t*16+(lane&15), cols = n0+wn*64+u*16+(lane>>4)*4.
// 3-product scheme: Ah*Bh + Ah*Bl + Al*Bh.
// ---------------------------------------------------------------------------
template <int K, bool BIAS, bool RELU, bool SPLIT_OUT>
__global__ __launch_bounds__(256) void k_gemm_stream(
    const u16* __restrict__ Ah, const u16* __restrict__ Al,
    const u16* __restrict__ Bth, const u16* __restrict__ Btl,
    const float* __restrict__ bias,
    u16* __restrict__ Ch, u16* __restrict__ Cl,
    int M, int N) {
    const int tid  = threadIdx.x;
    const int wid  = tid >> 6;
    const int lane = tid & 63;
    const int wm = wid >> 1;
    const int wn = wid & 1;
    const int row0 = blockIdx.y * 128;
    const int n0   = blockIdx.x * 128;

    const int fr = lane & 15;           // fragment row index within 16
    const int kg = (lane >> 4) * 8;     // fragment k offset (bf16 elements)

    // per-lane base element offsets (advance by 32 each K-step)
    const size_t bbase = (size_t)(n0 + wn * 64 + fr) * K + kg;
    const size_t abase = (size_t)(row0 + wm * 64 + fr) * K + kg;

    f4v acc[4][4];
    #pragma unroll
    for (int t = 0; t < 4; ++t)
        #pragma unroll
        for (int u = 0; u < 4; ++u)
            acc[t][u] = (f4v){0.f, 0.f, 0.f, 0.f};

    #pragma unroll 2
    for (int k0 = 0; k0 < K; k0 += 32) {
        s8v nh[4], nl[4], mh[4], ml[4];
        #pragma unroll
        for (int u = 0; u < 4; ++u) {
            const size_t b = bbase + (size_t)u * 16 * K + k0;
            nh[u] = *(const s8v*)(Bth + b);
            nl[u] = *(const s8v*)(Btl + b);
        }
        #pragma unroll
        for (int t = 0; t < 4; ++t) {
            const size_t a = abase + (size_t)t * 16 * K + k0;
            mh[t] = *(const s8v*)(Ah + a);
            ml[t] = *(const s8v*)(Al + a);
        }
        #pragma unroll
        for (int t = 0; t < 4; ++t) {
            #pragma unroll
            for (int u = 0; u < 4; ++u) {
                acc[t][u] = __builtin_amdgcn_mfma_f32_16x16x32_bf16(nh[u], mh[t], acc[t][u], 0, 0, 0);
                acc[t][u] = __builtin_amdgcn_mfma_f32_16x16x32_bf16(nl[u], mh[t], acc[t][u], 0, 0, 0);
                acc[t][u] = __builtin_amdgcn_mfma_f32_16x16x32_bf16(nh[u], ml[t], acc[t][u], 0, 0, 0);
            }
        }
    }

    const int ncol = (lane >> 4) * 4;   // 4 consecutive n-columns per lane
    #pragma unroll
    for (int t = 0; t < 4; ++t) {
        const int grow = row0 + wm * 64 + t * 16 + fr;
        if (grow < M) {
            #pragma unroll
            for (int u = 0; u < 4; ++u) {
                const int nb = n0 + wn * 64 + u * 16 + ncol;
                float v[4];
                #pragma unroll
                for (int r = 0; r < 4; ++r) {
                    float z = acc[t][u][r];
                    if constexpr (BIAS) z += bias[nb + r];
                    if constexpr (RELU) z = fmaxf(z, 0.f);
                    v[r] = z;
                }
                const size_t off = (size_t)grow * N + nb;
                u16 hi[4];
                #pragma unroll
                for (int r = 0; r < 4; ++r) hi[r] = f2bf(v[r]);
                uint2 ph;
                ph.x = (u32)hi[0] | ((u32)hi[1] << 16);
                ph.y = (u32)hi[2] | ((u32)hi[3] << 16);
                *reinterpret_cast<uint2*>(Ch + off) = ph;
                if constexpr (SPLIT_OUT) {
                    uint2 pl;
                    u16 lo[4];
                    #pragma unroll
                    for (int r = 0; r < 4; ++r) lo[r] = f2bf(v[r] - bf2f(hi[r]));
                    pl.x = (u32)lo[0] | ((u32)lo[1] << 16);
                    pl.y = (u32)lo[2] | ((u32)lo[3] << 16);
                    *reinterpret_cast<uint2*>(Cl + off) = pl;
                }
            }
        }
    }
}

// ---------------------------------------------------------------------------
// Aggregation from BF16 features: one wave per node, fp32 accumulate.
// Edge loop unrolled x8 with 4 independent accumulator sets.
// OUT_MODE: 0 = fp32, 1 = split bf16 pair.
// ---------------------------------------------------------------------------
template <int D, bool BIAS, bool RELU, int OUT_MODE>
__global__ __launch_bounds__(256) void k_agg(
    const u16* __restrict__ h, const int* __restrict__ row_ptr,
    const int2* __restrict__ edat,
    const float* __restrict__ dis, const float* __restrict__ bias,
    float* __restrict__ outf, u16* __restrict__ outh, u16* __restrict__ outl) {
    constexpr int V = D / 64;   // bf16 elems per lane: 4 (D=256) or 2 (D=128)
    const int wave = threadIdx.x >> 6;
    const int lane = threadIdx.x & 63;
    const int node = blockIdx.x * 4 + wave;
    if (node >= N_NODES) return;

    const int beg = row_ptr[node];
    const int end = row_ptr[node + 1];
    const int base = lane * V;

    float a[4][V];
    #pragma unroll
    for (int c = 0; c < 4; ++c)
        #pragma unroll
        for (int j = 0; j < V; ++j) a[c][j] = 0.f;

#define LOADV(dst, s) do {                                                    \
        const u16* p_ = h + (size_t)(s) * D + base;                           \
        if constexpr (V == 4) {                                               \
            uint2 t_ = *reinterpret_cast<const uint2*>(p_);                   \
            dst[0] = bflo(t_.x); dst[1] = bfhi(t_.x);                         \
            dst[2] = bflo(t_.y); dst[3] = bfhi(t_.y);                         \
        } else {                                                              \
            u32 t_ = *reinterpret_cast<const u32*>(p_);                       \
            dst[0] = bflo(t_); dst[1] = bfhi(t_);                             \
        }                                                                     \
    } while (0)

    int e = beg;
    for (; e + 8 <= end; e += 8) {
        int2 ed[8];
        float v[8][V];
        #pragma unroll
        for (int j = 0; j < 8; ++j) ed[j] = edat[e + j];
        #pragma unroll
        for (int j = 0; j < 8; ++j) LOADV(v[j], ed[j].x);
        #pragma unroll
        for (int j = 0; j < 8; ++j) {
            const float w = __int_as_float(ed[j].y);
            #pragma unroll
            for (int k = 0; k < V; ++k) a[j & 3][k] += v[j][k] * w;
        }
    }
    for (; e + 2 <= end; e += 2) {
        const int2 e0 = edat[e], e1 = edat[e + 1];
        float v0[V], v1[V];
        LOADV(v0, e0.x); LOADV(v1, e1.x);
        const float w0 = __int_as_float(e0.y), w1 = __int_as_float(e1.y);
        #pragma unroll
        for (int k = 0; k < V; ++k) { a[0][k] += v0[k] * w0; a[1][k] += v1[k] * w1; }
    }
    if (e < end) {
        const int2 e0 = edat[e];
        float v0[V];
        LOADV(v0, e0.x);
        const float w0 = __int_as_float(e0.y);
        #pragma unroll
        for (int k = 0; k < V; ++k) a[2][k] += v0[k] * w0;
    }

    // self loop: norm = dis[node]^2
    {
        float sw = dis[node];
        sw *= sw;
        float vs[V];
        LOADV(vs, node);
        #pragma unroll
        for (int k = 0; k < V; ++k) a[3][k] += vs[k] * sw;
    }
#undef LOADV

    float r[V];
    #pragma unroll
    for (int j = 0; j < V; ++j) {
        float v = (a[0][j] + a[1][j]) + (a[2][j] + a[3][j]);
        if constexpr (BIAS) v += bias[base + j];
        if constexpr (RELU) v = fmaxf(v, 0.f);
        r[j] = v;
    }

    const size_t off = (size_t)node * D + base;
    if constexpr (OUT_MODE == 1) {
        u16 hi[V], lo[V];
        #pragma unroll
        for (int j = 0; j < V; ++j) {
            hi[j] = f2bf(r[j]);
            lo[j] = f2bf(r[j] - bf2f(hi[j]));
        }
        if constexpr (V == 4) {
            uint2 ph, pl;
            ph.x = (u32)hi[0] | ((u32)hi[1] << 16);
            ph.y = (u32)hi[2] | ((u32)hi[3] << 16);
            pl.x = (u32)lo[0] | ((u32)lo[1] << 16);
            pl.y = (u32)lo[2] | ((u32)lo[3] << 16);
            *reinterpret_cast<uint2*>(outh + off) = ph;
            *reinterpret_cast<uint2*>(outl + off) = pl;
        } else {
            *reinterpret_cast<u32*>(outh + off) = (u32)hi[0] | ((u32)hi[1] << 16);
            *reinterpret_cast<u32*>(outl + off) = (u32)lo[0] | ((u32)lo[1] << 16);
        }
    } else {
        if constexpr (V == 4) {
            *reinterpret_cast<float4*>(outf + off) = make_float4(r[0], r[1], r[2], r[3]);
        } else {
            *reinterpret_cast<float2*>(outf + off) = make_float2(r[0], r[1]);
        }
    }
}

// ---------------------------------------------------------------------------

extern "C" void kernel_launch(void* const* d_in, const int* in_sizes, int n_in,
                              void* d_out, int out_size, void* d_ws, size_t ws_size,
                              hipStream_t stream) {
    const float* x  = (const float*)d_in[0];
    const int*   ei = (const int*)d_in[1];
    const float* W1 = (const float*)d_in[2];
    const float* b1 = (const float*)d_in[3];
    const float* W2 = (const float*)d_in[4];
    const float* b2 = (const float*)d_in[5];
    const float* W3 = (const float*)d_in[6];
    const float* b3 = (const float*)d_in[7];
    float* out = (float*)d_out;

    const int N = N_NODES;
    const int E = in_sizes[1] / 2;

    char* ws = (char*)d_ws;
    size_t o = 0;
    auto take = [&](size_t bytes) {
        void* p = ws + o;
        o += (bytes + 255) & ~(size_t)255;
        return p;
    };
    float* dis     = (float*)take((size_t)N * 4);
    int*   row_ptr = (int*)  take((size_t)(N + 1) * 4);
    int*   cnt_cur = (int*)  take((size_t)N * 4);
    int*   bsum    = (int*)  take((size_t)SCAN_B * 4);
    int2*  edat    = (int2*) take((size_t)E * 8);
    u16* wt1h = (u16*)take((size_t)256 * 128 * 2);
    u16* wt1l = (u16*)take((size_t)256 * 128 * 2);
    u16* wt2h = (u16*)take((size_t)256 * 256 * 2);
    u16* wt2l = (u16*)take((size_t)256 * 256 * 2);
    u16* wt3h = (u16*)take((size_t)128 * 256 * 2);
    u16* wt3l = (u16*)take((size_t)128 * 256 * 2);
    // liveness chain 2-coloring:
    //   slot1: xb -> h1 pair -> h2 pair   slot2: xa pair -> g2 -> g3
    char* slot1 = (char*)take((size_t)2 * M_PAD * 256 * 2);   // 102.5 MB
    char* slot2 = (char*)take((size_t)2 * M_PAD * 128 * 2);   // 51.2 MB
    (void)ws_size; (void)n_in; (void)out_size;

    u16* xb  = (u16*)slot1;
    u16* h1h = (u16*)slot1;
    u16* h1l = h1h + (size_t)M_PAD * 256;
    u16* h2h = (u16*)slot1;                 // after h1 dead (GEMM2 done)
    u16* h2l = h2h + (size_t)M_PAD * 256;
    u16* xah = (u16*)slot2;
    u16* xal = xah + (size_t)M_PAD * 128;
    u16* g2  = (u16*)slot2;                 // after xa dead (GEMM1 done)
    u16* g3  = (u16*)slot2;                 // after g2 dead (agg2 done)

    const int nb_nodes = (N + 255) / 256;
    const int nb_edges = (E + 255) / 256;

    // ---- graph prep (parallel scan) ----
    k_zero_int<<<nb_nodes, 256, 0, stream>>>(cnt_cur, N);
    k_count<<<nb_edges, 256, 0, stream>>>(ei, E, cnt_cur);
    k_scan_a<<<SCAN_B, 1024, 0, stream>>>(cnt_cur, row_ptr, bsum, dis, N);
    k_scan_b<<<1, 128, 0, stream>>>(bsum, row_ptr, SCAN_B, N, E);
    k_scan_c<<<SCAN_B, 1024, 0, stream>>>(row_ptr, bsum, cnt_cur, N);
    k_scatter<<<nb_edges, 256, 0, stream>>>(ei, E, dis, cnt_cur, edat);

    // ---- weight transpose+split, x -> bf16 ----
    k_prep_w<<<256, 256, 0, stream>>>(W1, wt1h, wt1l, 128, 256);
    k_prep_w<<<256, 256, 0, stream>>>(W2, wt2h, wt2l, 256, 256);
    k_prep_w<<<128, 256, 0, stream>>>(W3, wt3h, wt3l, 256, 128);
    const long n8 = (long)N * 128 / 8;
    k_x2bf<<<(int)((n8 + 255) / 256), 256, 0, stream>>>(x, xb, n8);

    const int agg_blocks = (N + 3) / 4;
    const int m_blocks = M_PAD / 128;  // 782

    // ---- layer 1: xa = A*xb (D=128) ; h1 = relu(xa@W1 + b1) [split out] ----
    k_agg<128, false, false, 1><<<agg_blocks, 256, 0, stream>>>(
        xb, row_ptr, edat, dis, nullptr, nullptr, xah, xal);
    k_gemm_stream<128, true, true, true><<<dim3(2, m_blocks), 256, 0, stream>>>(
        xah, xal, wt1h, wt1l, b1, h1h, h1l, N, 256);

    // ---- layer 2: g2 = h1@W2 [bf16 out] ; h2 = relu(A*g2 + b2) [split out] ----
    k_gemm_stream<256, false, false, false><<<dim3(2, m_blocks), 256, 0, stream>>>(
        h1h, h1l, wt2h, wt2l, nullptr, g2, nullptr, N, 256);
    k_agg<256, true, true, 1><<<agg_blocks, 256, 0, stream>>>(
        g2, row_ptr, edat, dis, b2, nullptr, h2h, h2l);

    // ---- layer 3: g3 = h2@W3 [bf16 out] ; out = A*g3 + b3 [fp32 out] ----
    k_gemm_stream<256, false, false, false><<<dim3(1, m_blocks), 256, 0, stream>>>(
        h2h, h2l, wt3h, wt3l, nullptr, g3, nullptr, N, 128);
    k_agg<128, true, false, 0><<<agg_blocks, 256, 0, stream>>>(
        g3, row_ptr, edat, dis, b3, out, nullptr, nullptr);
}

// Round 10
// 656.539 us; speedup vs baseline: 1.2059x; 1.2059x over previous
//
#include <hip/hip_runtime.h>
#include <hip/hip_bf16.h>

#define N_NODES 100000
#define M_PAD   100096   // 782 * 128 — GEMM A-buffers padded so staging never goes OOB
#define SCAN_B  98       // ceil(N_NODES / 1024)

typedef __attribute__((ext_vector_type(8))) short s8v;   // 8 x bf16 (4 VGPR) MFMA operand
typedef __attribute__((ext_vector_type(4))) float f4v;   // MFMA accumulator
typedef unsigned short u16;
typedef unsigned int   u32;

__device__ __forceinline__ u16 f2bf(float v) {
    __hip_bfloat16 b = __float2bfloat16(v);
    return __builtin_bit_cast(u16, b);
}
__device__ __forceinline__ float bf2f(u16 u) {
    u32 t = (u32)u << 16;
    return __builtin_bit_cast(float, t);
}
__device__ __forceinline__ float bflo(u32 p) { return __builtin_bit_cast(float, p << 16); }
__device__ __forceinline__ float bfhi(u32 p) { return __builtin_bit_cast(float, p & 0xffff0000u); }

// async global->LDS, 16B per lane; LDS dest is wave-uniform base + lane*16
__device__ __forceinline__ void gl_lds16(const void* g, void* l) {
    __builtin_amdgcn_global_load_lds(
        (const __attribute__((address_space(1))) void*)g,
        (__attribute__((address_space(3))) void*)l, 16, 0, 0);
}

// ---------------------------------------------------------------------------
// Graph prep
// ---------------------------------------------------------------------------

__global__ __launch_bounds__(256) void k_zero_int(int* __restrict__ p, int n) {
    int i = blockIdx.x * 256 + threadIdx.x;
    if (i < n) p[i] = 0;
}

__global__ __launch_bounds__(256) void k_count(const int* __restrict__ ei, int E,
                                               int* __restrict__ cnt) {
    for (int e = blockIdx.x * 256 + threadIdx.x; e < E; e += gridDim.x * 256)
        atomicAdd(&cnt[ei[E + e]], 1);
}

// scan phase A: per-block exclusive scan (1024 elems/block) + block sums + dis
__global__ __launch_bounds__(1024) void k_scan_a(const int* __restrict__ cnt,
                                                 int* __restrict__ row_ptr,
                                                 int* __restrict__ bsum,
                                                 float* __restrict__ dis, int n) {
    __shared__ int wsum[16];
    const int tid = threadIdx.x;
    const int lane = tid & 63;
    const int wv = tid >> 6;
    const int i = blockIdx.x * 1024 + tid;
    const int v = (i < n) ? cnt[i] : 0;
    if (i < n) dis[i] = 1.0f / sqrtf((float)(v + 1));
    int x = v;
    #pragma unroll
    for (int d = 1; d < 64; d <<= 1) {
        int t = __shfl_up(x, d, 64);
        if (lane >= d) x += t;
    }
    if (lane == 63) wsum[wv] = x;
    __syncthreads();
    int woff = 0, total = 0;
    #pragma unroll
    for (int w = 0; w < 16; ++w) {
        int s = wsum[w];
        if (w < wv) woff += s;
        total += s;
    }
    if (i < n) row_ptr[i] = woff + x - v;  // block-local exclusive
    if (tid == 0) bsum[blockIdx.x] = total;
}

// scan phase B: exclusive scan of SCAN_B block sums (1 block, 128 thr)
__global__ __launch_bounds__(128) void k_scan_b(int* __restrict__ bsum,
                                                int* __restrict__ row_ptr,
                                                int nparts, int n, int total_edges) {
    __shared__ int w0tot;
    const int tid = threadIdx.x;
    const int lane = tid & 63;
    const int v = (tid < nparts) ? bsum[tid] : 0;
    int x = v;
    #pragma unroll
    for (int d = 1; d < 64; d <<= 1) {
        int t = __shfl_up(x, d, 64);
        if (lane >= d) x += t;
    }
    if (tid == 63) w0tot = x;
    __syncthreads();
    int excl = x - v + ((tid >= 64) ? w0tot : 0);
    if (tid < nparts) bsum[tid] = excl;
    if (tid == 0) row_ptr[n] = total_edges;
}

// scan phase C: add block offset, init cursor
__global__ __launch_bounds__(1024) void k_scan_c(int* __restrict__ row_ptr,
                                                 const int* __restrict__ bsum,
                                                 int* __restrict__ cursor, int n) {
    const int i = blockIdx.x * 1024 + threadIdx.x;
    if (i < n) {
        const int r = row_ptr[i] + bsum[blockIdx.x];
        row_ptr[i] = r;
        cursor[i] = r;
    }
}

// counting-sort scatter: edge -> slot in dst's CSR row; pack (src, norm) as int2
__global__ __launch_bounds__(256) void k_scatter(const int* __restrict__ ei, int E,
                                                 const float* __restrict__ dis,
                                                 int* __restrict__ cursor,
                                                 int2* __restrict__ edat) {
    for (int e = blockIdx.x * 256 + threadIdx.x; e < E; e += gridDim.x * 256) {
        const int s = ei[e];
        const int d = ei[E + e];
        const int pos = atomicAdd(&cursor[d], 1);
        edat[pos] = make_int2(s, __float_as_int(dis[s] * dis[d]));
    }
}

// ---------------------------------------------------------------------------
// Weight prep: W[K][N] fp32 -> transposed split Wt_hi/Wt_lo [N][K] bf16
// ---------------------------------------------------------------------------
__global__ __launch_bounds__(256) void k_prep_w(const float* __restrict__ W,
                                                u16* __restrict__ Wth,
                                                u16* __restrict__ Wtl,
                                                int K, int N) {
    const int n = blockIdx.x;
    for (int k = threadIdx.x; k < K; k += 256) {
        float v = W[(size_t)k * N + n];
        u16 hi = f2bf(v);
        Wth[(size_t)n * K + k] = hi;
        Wtl[(size_t)n * K + k] = f2bf(v - bf2f(hi));
    }
}

// x fp32 -> bf16 (8 elems/thread)
__global__ __launch_bounds__(256) void k_x2bf(const float* __restrict__ x,
                                              u16* __restrict__ xb, long n8) {
    long i = (long)blockIdx.x * 256 + threadIdx.x;
    if (i >= n8) return;
    const float4 a = *reinterpret_cast<const float4*>(x + i * 8);
    const float4 b = *reinterpret_cast<const float4*>(x + i * 8 + 4);
    uint4 p;
    p.x = (u32)f2bf(a.x) | ((u32)f2bf(a.y) << 16);
    p.y = (u32)f2bf(a.z) | ((u32)f2bf(a.w) << 16);
    p.z = (u32)f2bf(b.x) | ((u32)f2bf(b.y) << 16);
    p.w = (u32)f2bf(b.z) | ((u32)f2bf(b.w) << 16);
    *reinterpret_cast<uint4*>(xb + i * 8) = p;
}

// ---------------------------------------------------------------------------
// 2-product MFMA GEMM: C = A @ (Wh + Wl)^T_storage, A single bf16.
// LDS staging via global_load_lds (round-6 proven structure), tile 128x128xBK32,
// 4 waves of 64x64. Swapped operands (a=W-frag, b=A-frag) so each lane holds
// 4 consecutive N-columns of one M-row -> vectorized row-major stores.
// ---------------------------------------------------------------------------
template <bool BIAS, bool RELU>
__global__ __launch_bounds__(256) void k_gemm2p(
    const u16* __restrict__ A,
    const u16* __restrict__ Bth, const u16* __restrict__ Btl,
    const float* __restrict__ bias,
    u16* __restrict__ Ch,
    int M, int N, int K) {
    __shared__ u16 As[128 * 32];
    __shared__ u16 Bhs[128 * 32];
    __shared__ u16 Bls[128 * 32];

    const int tid  = threadIdx.x;
    const int wid  = tid >> 6;
    const int lane = tid & 63;
    const int wm = wid >> 1;
    const int wn = wid & 1;
    const int row0 = blockIdx.y * 128;
    const int n0   = blockIdx.x * 128;

    const int srow  = lane >> 2;        // staging: row within 16-row group
    const int sbyte = (lane & 3) * 16;  // staging: byte offset within 64B row
    const int fr = lane & 15;           // fragment row index within 16
    const int kg = (lane >> 4) * 8;     // fragment k offset (bf16 elements)

    f4v acc[4][4];
    #pragma unroll
    for (int t = 0; t < 4; ++t)
        #pragma unroll
        for (int u = 0; u < 4; ++u)
            acc[t][u] = (f4v){0.f, 0.f, 0.f, 0.f};

    for (int k0 = 0; k0 < K; k0 += 32) {
        // stage 128x32 bf16 tiles: 6 gl_lds per wave
        #pragma unroll
        for (int g = 0; g < 2; ++g) {
            const int rloc = wid * 32 + g * 16;
            const size_t ga = (size_t)(row0 + rloc + srow) * K + k0;
            gl_lds16((const char*)(A + ga) + sbyte, &As[rloc * 32]);
            const size_t gb = (size_t)(n0 + rloc + srow) * K + k0;
            gl_lds16((const char*)(Bth + gb) + sbyte, &Bhs[rloc * 32]);
            gl_lds16((const char*)(Btl + gb) + sbyte, &Bls[rloc * 32]);
        }
        __syncthreads();

        // a-operands from Wt (n side), b-operands from A (m side)
        s8v nh[4], nl[4];
        #pragma unroll
        for (int u = 0; u < 4; ++u) {
            const int rb = (wn * 64 + u * 16 + fr) * 32 + kg;
            nh[u] = *(const s8v*)&Bhs[rb];
            nl[u] = *(const s8v*)&Bls[rb];
        }
        #pragma unroll
        for (int t = 0; t < 4; ++t) {
            const int ra = (wm * 64 + t * 16 + fr) * 32 + kg;
            const s8v m = *(const s8v*)&As[ra];
            #pragma unroll
            for (int u = 0; u < 4; ++u) {
                acc[t][u] = __builtin_amdgcn_mfma_f32_16x16x32_bf16(nh[u], m, acc[t][u], 0, 0, 0);
                acc[t][u] = __builtin_amdgcn_mfma_f32_16x16x32_bf16(nl[u], m, acc[t][u], 0, 0, 0);
            }
        }
        __syncthreads();
    }

    const int ncol = (lane >> 4) * 4;   // 4 consecutive n-columns per lane
    #pragma unroll
    for (int t = 0; t < 4; ++t) {
        const int grow = row0 + wm * 64 + t * 16 + fr;
        if (grow < M) {
            #pragma unroll
            for (int u = 0; u < 4; ++u) {
                const int nb = n0 + wn * 64 + u * 16 + ncol;
                float v[4];
                #pragma unroll
                for (int r = 0; r < 4; ++r) {
                    float z = acc[t][u][r];
                    if constexpr (BIAS) z += bias[nb + r];
                    if constexpr (RELU) z = fmaxf(z, 0.f);
                    v[r] = z;
                }
                const size_t off = (size_t)grow * N + nb;
                u16 hi[4];
                #pragma unroll
                for (int r = 0; r < 4; ++r) hi[r] = f2bf(v[r]);
                uint2 ph;
                ph.x = (u32)hi[0] | ((u32)hi[1] << 16);
                ph.y = (u32)hi[2] | ((u32)hi[3] << 16);
                *reinterpret_cast<uint2*>(Ch + off) = ph;
            }
        }
    }
}

// ---------------------------------------------------------------------------
// Aggregation from BF16 features: one wave per node, fp32 accumulate.
// Edge loop unrolled x8 with 4 independent accumulator sets.
// OUT_MODE: 0 = fp32, 1 = bf16.
// ---------------------------------------------------------------------------
template <int D, bool BIAS, bool RELU, int OUT_MODE>
__global__ __launch_bounds__(256) void k_agg(
    const u16* __restrict__ h, const int* __restrict__ row_ptr,
    const int2* __restrict__ edat,
    const float* __restrict__ dis, const float* __restrict__ bias,
    float* __restrict__ outf, u16* __restrict__ outh) {
    constexpr int V = D / 64;   // bf16 elems per lane: 4 (D=256) or 2 (D=128)
    const int wave = threadIdx.x >> 6;
    const int lane = threadIdx.x & 63;
    const int node = blockIdx.x * 4 + wave;
    if (node >= N_NODES) return;

    const int beg = row_ptr[node];
    const int end = row_ptr[node + 1];
    const int base = lane * V;

    float a[4][V];
    #pragma unroll
    for (int c = 0; c < 4; ++c)
        #pragma unroll
        for (int j = 0; j < V; ++j) a[c][j] = 0.f;

#define LOADV(dst, s) do {                                                    \
        const u16* p_ = h + (size_t)(s) * D + base;                           \
        if constexpr (V == 4) {                                               \
            uint2 t_ = *reinterpret_cast<const uint2*>(p_);                   \
            dst[0] = bflo(t_.x); dst[1] = bfhi(t_.x);                         \
            dst[2] = bflo(t_.y); dst[3] = bfhi(t_.y);                         \
        } else {                                                              \
            u32 t_ = *reinterpret_cast<const u32*>(p_);                       \
            dst[0] = bflo(t_); dst[1] = bfhi(t_);                             \
        }                                                                     \
    } while (0)

    int e = beg;
    for (; e + 8 <= end; e += 8) {
        int2 ed[8];
        float v[8][V];
        #pragma unroll
        for (int j = 0; j < 8; ++j) ed[j] = edat[e + j];
        #pragma unroll
        for (int j = 0; j < 8; ++j) LOADV(v[j], ed[j].x);
        #pragma unroll
        for (int j = 0; j < 8; ++j) {
            const float w = __int_as_float(ed[j].y);
            #pragma unroll
            for (int k = 0; k < V; ++k) a[j & 3][k] += v[j][k] * w;
        }
    }
    for (; e + 2 <= end; e += 2) {
        const int2 e0 = edat[e], e1 = edat[e + 1];
        float v0[V], v1[V];
        LOADV(v0, e0.x); LOADV(v1, e1.x);
        const float w0 = __int_as_float(e0.y), w1 = __int_as_float(e1.y);
        #pragma unroll
        for (int k = 0; k < V; ++k) { a[0][k] += v0[k] * w0; a[1][k] += v1[k] * w1; }
    }
    if (e < end) {
        const int2 e0 = edat[e];
        float v0[V];
        LOADV(v0, e0.x);
        const float w0 = __int_as_float(e0.y);
        #pragma unroll
        for (int k = 0; k < V; ++k) a[2][k] += v0[k] * w0;
    }

    // self loop: norm = dis[node]^2
    {
        float sw = dis[node];
        sw *= sw;
        float vs[V];
        LOADV(vs, node);
        #pragma unroll
        for (int k = 0; k < V; ++k) a[3][k] += vs[k] * sw;
    }
#undef LOADV

    float r[V];
    #pragma unroll
    for (int j = 0; j < V; ++j) {
        float v = (a[0][j] + a[1][j]) + (a[2][j] + a[3][j]);
        if constexpr (BIAS) v += bias[base + j];
        if constexpr (RELU) v = fmaxf(v, 0.f);
        r[j] = v;
    }

    const size_t off = (size_t)node * D + base;
    if constexpr (OUT_MODE == 1) {
        u16 hi[V];
        #pragma unroll
        for (int j = 0; j < V; ++j) hi[j] = f2bf(r[j]);
        if constexpr (V == 4) {
            uint2 ph;
            ph.x = (u32)hi[0] | ((u32)hi[1] << 16);
            ph.y = (u32)hi[2] | ((u32)hi[3] << 16);
            *reinterpret_cast<uint2*>(outh + off) = ph;
        } else {
            *reinterpret_cast<u32*>(outh + off) = (u32)hi[0] | ((u32)hi[1] << 16);
        }
    } else {
        if constexpr (V == 4) {
            *reinterpret_cast<float4*>(outf + off) = make_float4(r[0], r[1], r[2], r[3]);
        } else {
            *reinterpret_cast<float2*>(outf + off) = make_float2(r[0], r[1]);
        }
    }
}

// ---------------------------------------------------------------------------

extern "C" void kernel_launch(void* const* d_in, const int* in_sizes, int n_in,
                              void* d_out, int out_size, void* d_ws, size_t ws_size,
                              hipStream_t stream) {
    const float* x  = (const float*)d_in[0];
    const int*   ei = (const int*)d_in[1];
    const float* W1 = (const float*)d_in[2];
    const float* b1 = (const float*)d_in[3];
    const float* W2 = (const float*)d_in[4];
    const float* b2 = (const float*)d_in[5];
    const float* W3 = (const float*)d_in[6];
    const float* b3 = (const float*)d_in[7];
    float* out = (float*)d_out;

    const int N = N_NODES;
    const int E = in_sizes[1] / 2;

    char* ws = (char*)d_ws;
    size_t o = 0;
    auto take = [&](size_t bytes) {
        void* p = ws + o;
        o += (bytes + 255) & ~(size_t)255;
        return p;
    };
    float* dis     = (float*)take((size_t)N * 4);
    int*   row_ptr = (int*)  take((size_t)(N + 1) * 4);
    int*   cnt_cur = (int*)  take((size_t)N * 4);
    int*   bsum    = (int*)  take((size_t)SCAN_B * 4);
    int2*  edat    = (int2*) take((size_t)E * 8);
    u16* wt1h = (u16*)take((size_t)256 * 128 * 2);
    u16* wt1l = (u16*)take((size_t)256 * 128 * 2);
    u16* wt2h = (u16*)take((size_t)256 * 256 * 2);
    u16* wt2l = (u16*)take((size_t)256 * 256 * 2);
    u16* wt3h = (u16*)take((size_t)128 * 256 * 2);
    u16* wt3l = (u16*)take((size_t)128 * 256 * 2);
    // liveness chain 2-coloring (all activations single bf16):
    //   slot1: xb (25.6MB) -> h1 (51.2MB) -> h2 (51.2MB)
    //   slot2: xa (25.6MB) -> g2 (51.2MB) -> g3 (25.6MB)
    char* slot1 = (char*)take((size_t)M_PAD * 256 * 2);   // 51.2 MB
    char* slot2 = (char*)take((size_t)M_PAD * 256 * 2);   // 51.2 MB
    (void)ws_size; (void)n_in; (void)out_size;

    u16* xb = (u16*)slot1;
    u16* h1 = (u16*)slot1;   // after xb dead (agg1 done)
    u16* h2 = (u16*)slot1;   // after h1 dead (GEMM2 done)
    u16* xa = (u16*)slot2;
    u16* g2 = (u16*)slot2;   // after xa dead (GEMM1 done)
    u16* g3 = (u16*)slot2;   // after g2 dead (agg2 done)

    const int nb_nodes = (N + 255) / 256;
    const int nb_edges = (E + 255) / 256;

    // ---- graph prep (parallel scan) ----
    k_zero_int<<<nb_nodes, 256, 0, stream>>>(cnt_cur, N);
    k_count<<<nb_edges, 256, 0, stream>>>(ei, E, cnt_cur);
    k_scan_a<<<SCAN_B, 1024, 0, stream>>>(cnt_cur, row_ptr, bsum, dis, N);
    k_scan_b<<<1, 128, 0, stream>>>(bsum, row_ptr, SCAN_B, N, E);
    k_scan_c<<<SCAN_B, 1024, 0, stream>>>(row_ptr, bsum, cnt_cur, N);
    k_scatter<<<nb_edges, 256, 0, stream>>>(ei, E, dis, cnt_cur, edat);

    // ---- weight transpose+split, x -> bf16 ----
    k_prep_w<<<256, 256, 0, stream>>>(W1, wt1h, wt1l, 128, 256);
    k_prep_w<<<256, 256, 0, stream>>>(W2, wt2h, wt2l, 256, 256);
    k_prep_w<<<128, 256, 0, stream>>>(W3, wt3h, wt3l, 256, 128);
    const long n8 = (long)N * 128 / 8;
    k_x2bf<<<(int)((n8 + 255) / 256), 256, 0, stream>>>(x, xb, n8);

    const int agg_blocks = (N + 3) / 4;
    const int m_blocks = M_PAD / 128;  // 782

    // ---- layer 1: xa = A*xb (D=128) ; h1 = relu(xa@W1 + b1) ----
    k_agg<128, false, false, 1><<<agg_blocks, 256, 0, stream>>>(
        xb, row_ptr, edat, dis, nullptr, nullptr, xa);
    k_gemm2p<true, true><<<dim3(2, m_blocks), 256, 0, stream>>>(
        xa, wt1h, wt1l, b1, h1, N, 256, 128);

    // ---- layer 2: g2 = h1@W2 ; h2 = relu(A*g2 + b2) ----
    k_gemm2p<false, false><<<dim3(2, m_blocks), 256, 0, stream>>>(
        h1, wt2h, wt2l, nullptr, g2, N, 256, 256);
    k_agg<256, true, true, 1><<<agg_blocks, 256, 0, stream>>>(
        g2, row_ptr, edat, dis, b2, nullptr, h2);

    // ---- layer 3: g3 = h2@W3 ; out = A*g3 + b3 [fp32 out] ----
    k_gemm2p<false, false><<<dim3(1, m_blocks), 256, 0, stream>>>(
        h2, wt3h, wt3l, nullptr, g3, N, 128, 256);
    k_agg<128, true, false, 0><<<agg_blocks, 256, 0, stream>>>(
        g3, row_ptr, edat, dis, b3, out, nullptr);
}

// Round 11
// 627.300 us; speedup vs baseline: 1.2621x; 1.0466x over previous
//
#include <hip/hip_runtime.h>
#include <hip/hip_bf16.h>

#define N_NODES 100000
#define M_PAD   100096   // 391 * 256 — GEMM A-buffers padded so staging never goes OOB
#define SCAN_B  98       // ceil(N_NODES / 1024)

typedef __attribute__((ext_vector_type(8))) short s8v;   // 8 x bf16 (4 VGPR) MFMA operand
typedef __attribute__((ext_vector_type(4))) float f4v;   // MFMA accumulator
typedef unsigned short u16;
typedef unsigned int   u32;

__device__ __forceinline__ u16 f2bf(float v) {
    __hip_bfloat16 b = __float2bfloat16(v);
    return __builtin_bit_cast(u16, b);
}
__device__ __forceinline__ float bf2f(u16 u) {
    u32 t = (u32)u << 16;
    return __builtin_bit_cast(float, t);
}
__device__ __forceinline__ float bflo(u32 p) { return __builtin_bit_cast(float, p << 16); }
__device__ __forceinline__ float bfhi(u32 p) { return __builtin_bit_cast(float, p & 0xffff0000u); }

// async global->LDS, 16B per lane; LDS dest is wave-uniform base + lane*16
__device__ __forceinline__ void gl_lds16(const void* g, void* l) {
    __builtin_amdgcn_global_load_lds(
        (const __attribute__((address_space(1))) void*)g,
        (__attribute__((address_space(3))) void*)l, 16, 0, 0);
}

// ---------------------------------------------------------------------------
// Graph prep
// ---------------------------------------------------------------------------

__global__ __launch_bounds__(256) void k_zero_int(int* __restrict__ p, int n) {
    int i = blockIdx.x * 256 + threadIdx.x;
    if (i < n) p[i] = 0;
}

// histogram of dst, 2 edges per thread (int2 loads)
__global__ __launch_bounds__(256) void k_count(const int* __restrict__ ei, int E,
                                               int* __restrict__ cnt) {
    const int h = E >> 1;
    for (int i = blockIdx.x * 256 + threadIdx.x; i < h; i += gridDim.x * 256) {
        const int2 d2 = *reinterpret_cast<const int2*>(ei + E + 2 * i);
        atomicAdd(&cnt[d2.x], 1);
        atomicAdd(&cnt[d2.y], 1);
    }
    if (blockIdx.x == 0 && threadIdx.x == 0 && (E & 1))
        atomicAdd(&cnt[ei[E + E - 1]], 1);
}

// scan phase A: per-block exclusive scan (1024 elems/block) + block sums + dis
__global__ __launch_bounds__(1024) void k_scan_a(const int* __restrict__ cnt,
                                                 int* __restrict__ row_ptr,
                                                 int* __restrict__ bsum,
                                                 float* __restrict__ dis, int n) {
    __shared__ int wsum[16];
    const int tid = threadIdx.x;
    const int lane = tid & 63;
    const int wv = tid >> 6;
    const int i = blockIdx.x * 1024 + tid;
    const int v = (i < n) ? cnt[i] : 0;
    if (i < n) dis[i] = 1.0f / sqrtf((float)(v + 1));
    int x = v;
    #pragma unroll
    for (int d = 1; d < 64; d <<= 1) {
        int t = __shfl_up(x, d, 64);
        if (lane >= d) x += t;
    }
    if (lane == 63) wsum[wv] = x;
    __syncthreads();
    int woff = 0, total = 0;
    #pragma unroll
    for (int w = 0; w < 16; ++w) {
        int s = wsum[w];
        if (w < wv) woff += s;
        total += s;
    }
    if (i < n) row_ptr[i] = woff + x - v;  // block-local exclusive
    if (tid == 0) bsum[blockIdx.x] = total;
}

// scan phase B: exclusive scan of SCAN_B block sums (1 block, 128 thr)
__global__ __launch_bounds__(128) void k_scan_b(int* __restrict__ bsum,
                                                int* __restrict__ row_ptr,
                                                int nparts, int n, int total_edges) {
    __shared__ int w0tot;
    const int tid = threadIdx.x;
    const int lane = tid & 63;
    const int v = (tid < nparts) ? bsum[tid] : 0;
    int x = v;
    #pragma unroll
    for (int d = 1; d < 64; d <<= 1) {
        int t = __shfl_up(x, d, 64);
        if (lane >= d) x += t;
    }
    if (tid == 63) w0tot = x;
    __syncthreads();
    int excl = x - v + ((tid >= 64) ? w0tot : 0);
    if (tid < nparts) bsum[tid] = excl;
    if (tid == 0) row_ptr[n] = total_edges;
}

// scan phase C: add block offset, init cursor
__global__ __launch_bounds__(1024) void k_scan_c(int* __restrict__ row_ptr,
                                                 const int* __restrict__ bsum,
                                                 int* __restrict__ cursor, int n) {
    const int i = blockIdx.x * 1024 + threadIdx.x;
    if (i < n) {
        const int r = row_ptr[i] + bsum[blockIdx.x];
        row_ptr[i] = r;
        cursor[i] = r;
    }
}

// counting-sort scatter, 2 edges per thread (int2 loads); pack (src, norm)
__global__ __launch_bounds__(256) void k_scatter(const int* __restrict__ ei, int E,
                                                 const float* __restrict__ dis,
                                                 int* __restrict__ cursor,
                                                 int2* __restrict__ edat) {
    const int h = E >> 1;
    for (int i = blockIdx.x * 256 + threadIdx.x; i < h; i += gridDim.x * 256) {
        const int2 s2 = *reinterpret_cast<const int2*>(ei + 2 * i);
        const int2 d2 = *reinterpret_cast<const int2*>(ei + E + 2 * i);
        const int p0 = atomicAdd(&cursor[d2.x], 1);
        edat[p0] = make_int2(s2.x, __float_as_int(dis[s2.x] * dis[d2.x]));
        const int p1 = atomicAdd(&cursor[d2.y], 1);
        edat[p1] = make_int2(s2.y, __float_as_int(dis[s2.y] * dis[d2.y]));
    }
    if (blockIdx.x == 0 && threadIdx.x == 0 && (E & 1)) {
        const int e = E - 1;
        const int s = ei[e], d = ei[E + e];
        const int pos = atomicAdd(&cursor[d], 1);
        edat[pos] = make_int2(s, __float_as_int(dis[s] * dis[d]));
    }
}

// ---------------------------------------------------------------------------
// Weight prep (all 3 layers in one launch):
// W[K][N] fp32 -> transposed split Wt_hi/Wt_lo [N][K] bf16
// blocks 0..255 -> W1 (K=128,N=256); 256..511 -> W2 (256,256); 512..639 -> W3 (256,128)
// ---------------------------------------------------------------------------
__global__ __launch_bounds__(256) void k_prep_w_all(
    const float* __restrict__ W1, const float* __restrict__ W2,
    const float* __restrict__ W3,
    u16* __restrict__ w1h, u16* __restrict__ w1l,
    u16* __restrict__ w2h, u16* __restrict__ w2l,
    u16* __restrict__ w3h, u16* __restrict__ w3l) {
    const int b = blockIdx.x;
    const float* W; u16 *H, *L; int K, N, n;
    if (b < 256)      { W = W1; H = w1h; L = w1l; K = 128; N = 256; n = b; }
    else if (b < 512) { W = W2; H = w2h; L = w2l; K = 256; N = 256; n = b - 256; }
    else              { W = W3; H = w3h; L = w3l; K = 256; N = 128; n = b - 512; }
    for (int k = threadIdx.x; k < K; k += 256) {
        float v = W[(size_t)k * N + n];
        u16 hi = f2bf(v);
        H[(size_t)n * K + k] = hi;
        L[(size_t)n * K + k] = f2bf(v - bf2f(hi));
    }
}

// x fp32 -> bf16 (8 elems/thread)
__global__ __launch_bounds__(256) void k_x2bf(const float* __restrict__ x,
                                              u16* __restrict__ xb, long n8) {
    long i = (long)blockIdx.x * 256 + threadIdx.x;
    if (i >= n8) return;
    const float4 a = *reinterpret_cast<const float4*>(x + i * 8);
    const float4 b = *reinterpret_cast<const float4*>(x + i * 8 + 4);
    uint4 p;
    p.x = (u32)f2bf(a.x) | ((u32)f2bf(a.y) << 16);
    p.y = (u32)f2bf(a.z) | ((u32)f2bf(a.w) << 16);
    p.z = (u32)f2bf(b.x) | ((u32)f2bf(b.y) << 16);
    p.w = (u32)f2bf(b.z) | ((u32)f2bf(b.w) << 16);
    *reinterpret_cast<uint4*>(xb + i * 8) = p;
}

// ---------------------------------------------------------------------------
// 2-product MFMA GEMM: C = A @ (Wh + Wl)^T_storage, A single bf16.
// Tile 256x128xBK32, 512 threads = 8 waves (4 wm x 2 wn) of 64x64 each.
// Halved barrier-event count vs 128x128: same per-block iters, half the blocks.
// LDS 32KB -> 2 blocks/CU at <=128 VGPR (launch_bounds 512,4).
// Swapped operands (a=W-frag, b=A-frag): lane holds 4 consecutive N-cols of
// one M-row -> vectorized row-major stores. BK=32 banking is conflict-free
// (b128 reads cover all 32 banks uniformly, 8 accesses/bank = floor).
// ---------------------------------------------------------------------------
template <bool BIAS, bool RELU>
__global__ __launch_bounds__(512, 4) void k_gemm2p(
    const u16* __restrict__ A,
    const u16* __restrict__ Bth, const u16* __restrict__ Btl,
    const float* __restrict__ bias,
    u16* __restrict__ Ch,
    int M, int N, int K) {
    __shared__ u16 As[256 * 32];    // 16 KB
    __shared__ u16 Bhs[128 * 32];   //  8 KB
    __shared__ u16 Bls[128 * 32];   //  8 KB

    const int tid  = threadIdx.x;
    const int wid  = tid >> 6;      // 0..7
    const int lane = tid & 63;
    const int wm = wid >> 1;        // 0..3
    const int wn = wid & 1;         // 0..1
    const int row0 = blockIdx.y * 256;
    const int n0   = blockIdx.x * 128;

    const int srow  = lane >> 2;        // staging: row within 16-row group
    const int sbyte = (lane & 3) * 16;  // staging: byte offset within 64B row
    const int fr = lane & 15;           // fragment row index within 16
    const int kg = (lane >> 4) * 8;     // fragment k offset (bf16 elements)

    f4v acc[4][4];
    #pragma unroll
    for (int t = 0; t < 4; ++t)
        #pragma unroll
        for (int u = 0; u < 4; ++u)
            acc[t][u] = (f4v){0.f, 0.f, 0.f, 0.f};

    for (int k0 = 0; k0 < K; k0 += 32) {
        // A tile 256x32: 2 gl_lds per wave (16 rows each)
        #pragma unroll
        for (int g = 0; g < 2; ++g) {
            const int rloc = wid * 32 + g * 16;
            const size_t ga = (size_t)(row0 + rloc + srow) * K + k0;
            gl_lds16((const char*)(A + ga) + sbyte, &As[rloc * 32]);
        }
        // B tiles 128x32 (hi+lo): 1 gl_lds each per wave
        {
            const int rloc = wid * 16;
            const size_t gb = (size_t)(n0 + rloc + srow) * K + k0;
            gl_lds16((const char*)(Bth + gb) + sbyte, &Bhs[rloc * 32]);
            gl_lds16((const char*)(Btl + gb) + sbyte, &Bls[rloc * 32]);
        }
        __syncthreads();

        // a-operands from Wt (n side), b-operands from A (m side)
        s8v nh[4], nl[4];
        #pragma unroll
        for (int u = 0; u < 4; ++u) {
            const int rb = (wn * 64 + u * 16 + fr) * 32 + kg;
            nh[u] = *(const s8v*)&Bhs[rb];
            nl[u] = *(const s8v*)&Bls[rb];
        }
        #pragma unroll
        for (int t = 0; t < 4; ++t) {
            const int ra = (wm * 64 + t * 16 + fr) * 32 + kg;
            const s8v m = *(const s8v*)&As[ra];
            #pragma unroll
            for (int u = 0; u < 4; ++u) {
                acc[t][u] = __builtin_amdgcn_mfma_f32_16x16x32_bf16(nh[u], m, acc[t][u], 0, 0, 0);
                acc[t][u] = __builtin_amdgcn_mfma_f32_16x16x32_bf16(nl[u], m, acc[t][u], 0, 0, 0);
            }
        }
        __syncthreads();
    }

    const int ncol = (lane >> 4) * 4;   // 4 consecutive n-columns per lane
    #pragma unroll
    for (int t = 0; t < 4; ++t) {
        const int grow = row0 + wm * 64 + t * 16 + fr;
        if (grow < M) {
            #pragma unroll
            for (int u = 0; u < 4; ++u) {
                const int nb = n0 + wn * 64 + u * 16 + ncol;
                float v[4];
                #pragma unroll
                for (int r = 0; r < 4; ++r) {
                    float z = acc[t][u][r];
                    if constexpr (BIAS) z += bias[nb + r];
                    if constexpr (RELU) z = fmaxf(z, 0.f);
                    v[r] = z;
                }
                const size_t off = (size_t)grow * N + nb;
                u16 hi[4];
                #pragma unroll
                for (int r = 0; r < 4; ++r) hi[r] = f2bf(v[r]);
                uint2 ph;
                ph.x = (u32)hi[0] | ((u32)hi[1] << 16);
                ph.y = (u32)hi[2] | ((u32)hi[3] << 16);
                *reinterpret_cast<uint2*>(Ch + off) = ph;
            }
        }
    }
}

// ---------------------------------------------------------------------------
// Aggregation from BF16 features: one wave per node, fp32 accumulate.
// Edge loop unrolled x8 with 4 independent accumulator sets.
// OUT_MODE: 0 = fp32, 1 = bf16.
// ---------------------------------------------------------------------------
template <int D, bool BIAS, bool RELU, int OUT_MODE>
__global__ __launch_bounds__(256) void k_agg(
    const u16* __restrict__ h, const int* __restrict__ row_ptr,
    const int2* __restrict__ edat,
    const float* __restrict__ dis, const float* __restrict__ bias,
    float* __restrict__ outf, u16* __restrict__ outh) {
    constexpr int V = D / 64;   // bf16 elems per lane: 4 (D=256) or 2 (D=128)
    const int wave = threadIdx.x >> 6;
    const int lane = threadIdx.x & 63;
    const int node = blockIdx.x * 4 + wave;
    if (node >= N_NODES) return;

    const int beg = row_ptr[node];
    const int end = row_ptr[node + 1];
    const int base = lane * V;

    float a[4][V];
    #pragma unroll
    for (int c = 0; c < 4; ++c)
        #pragma unroll
        for (int j = 0; j < V; ++j) a[c][j] = 0.f;

#define LOADV(dst, s) do {                                                    \
        const u16* p_ = h + (size_t)(s) * D + base;                           \
        if constexpr (V == 4) {                                               \
            uint2 t_ = *reinterpret_cast<const uint2*>(p_);                   \
            dst[0] = bflo(t_.x); dst[1] = bfhi(t_.x);                         \
            dst[2] = bflo(t_.y); dst[3] = bfhi(t_.y);                         \
        } else {                                                              \
            u32 t_ = *reinterpret_cast<const u32*>(p_);                       \
            dst[0] = bflo(t_); dst[1] = bfhi(t_);                             \
        }                                                                     \
    } while (0)

    int e = beg;
    for (; e + 8 <= end; e += 8) {
        int2 ed[8];
        float v[8][V];
        #pragma unroll
        for (int j = 0; j < 8; ++j) ed[j] = edat[e + j];
        #pragma unroll
        for (int j = 0; j < 8; ++j) LOADV(v[j], ed[j].x);
        #pragma unroll
        for (int j = 0; j < 8; ++j) {
            const float w = __int_as_float(ed[j].y);
            #pragma unroll
            for (int k = 0; k < V; ++k) a[j & 3][k] += v[j][k] * w;
        }
    }
    for (; e + 2 <= end; e += 2) {
        const int2 e0 = edat[e], e1 = edat[e + 1];
        float v0[V], v1[V];
        LOADV(v0, e0.x); LOADV(v1, e1.x);
        const float w0 = __int_as_float(e0.y), w1 = __int_as_float(e1.y);
        #pragma unroll
        for (int k = 0; k < V; ++k) { a[0][k] += v0[k] * w0; a[1][k] += v1[k] * w1; }
    }
    if (e < end) {
        const int2 e0 = edat[e];
        float v0[V];
        LOADV(v0, e0.x);
        const float w0 = __int_as_float(e0.y);
        #pragma unroll
        for (int k = 0; k < V; ++k) a[2][k] += v0[k] * w0;
    }

    // self loop: norm = dis[node]^2
    {
        float sw = dis[node];
        sw *= sw;
        float vs[V];
        LOADV(vs, node);
        #pragma unroll
        for (int k = 0; k < V; ++k) a[3][k] += vs[k] * sw;
    }
#undef LOADV

    float r[V];
    #pragma unroll
    for (int j = 0; j < V; ++j) {
        float v = (a[0][j] + a[1][j]) + (a[2][j] + a[3][j]);
        if constexpr (BIAS) v += bias[base + j];
        if constexpr (RELU) v = fmaxf(v, 0.f);
        r[j] = v;
    }

    const size_t off = (size_t)node * D + base;
    if constexpr (OUT_MODE == 1) {
        u16 hi[V];
        #pragma unroll
        for (int j = 0; j < V; ++j) hi[j] = f2bf(r[j]);
        if constexpr (V == 4) {
            uint2 ph;
            ph.x = (u32)hi[0] | ((u32)hi[1] << 16);
            ph.y = (u32)hi[2] | ((u32)hi[3] << 16);
            *reinterpret_cast<uint2*>(outh + off) = ph;
        } else {
            *reinterpret_cast<u32*>(outh + off) = (u32)hi[0] | ((u32)hi[1] << 16);
        }
    } else {
        if constexpr (V == 4) {
            *reinterpret_cast<float4*>(outf + off) = make_float4(r[0], r[1], r[2], r[3]);
        } else {
            *reinterpret_cast<float2*>(outf + off) = make_float2(r[0], r[1]);
        }
    }
}

// ---------------------------------------------------------------------------

extern "C" void kernel_launch(void* const* d_in, const int* in_sizes, int n_in,
                              void* d_out, int out_size, void* d_ws, size_t ws_size,
                              hipStream_t stream) {
    const float* x  = (const float*)d_in[0];
    const int*   ei = (const int*)d_in[1];
    const float* W1 = (const float*)d_in[2];
    const float* b1 = (const float*)d_in[3];
    const float* W2 = (const float*)d_in[4];
    const float* b2 = (const float*)d_in[5];
    const float* W3 = (const float*)d_in[6];
    const float* b3 = (const float*)d_in[7];
    float* out = (float*)d_out;

    const int N = N_NODES;
    const int E = in_sizes[1] / 2;

    char* ws = (char*)d_ws;
    size_t o = 0;
    auto take = [&](size_t bytes) {
        void* p = ws + o;
        o += (bytes + 255) & ~(size_t)255;
        return p;
    };
    float* dis     = (float*)take((size_t)N * 4);
    int*   row_ptr = (int*)  take((size_t)(N + 1) * 4);
    int*   cnt_cur = (int*)  take((size_t)N * 4);
    int*   bsum    = (int*)  take((size_t)SCAN_B * 4);
    int2*  edat    = (int2*) take((size_t)E * 8);
    u16* wt1h = (u16*)take((size_t)256 * 128 * 2);
    u16* wt1l = (u16*)take((size_t)256 * 128 * 2);
    u16* wt2h = (u16*)take((size_t)256 * 256 * 2);
    u16* wt2l = (u16*)take((size_t)256 * 256 * 2);
    u16* wt3h = (u16*)take((size_t)128 * 256 * 2);
    u16* wt3l = (u16*)take((size_t)128 * 256 * 2);
    // liveness chain 2-coloring (all activations single bf16):
    //   slot1: xb (25.6MB) -> h1 (51.2MB) -> h2 (51.2MB)
    //   slot2: xa (25.6MB) -> g2 (51.2MB) -> g3 (25.6MB)
    char* slot1 = (char*)take((size_t)M_PAD * 256 * 2);   // 51.2 MB
    char* slot2 = (char*)take((size_t)M_PAD * 256 * 2);   // 51.2 MB
    (void)ws_size; (void)n_in; (void)out_size;

    u16* xb = (u16*)slot1;
    u16* h1 = (u16*)slot1;   // after xb dead (agg1 done)
    u16* h2 = (u16*)slot1;   // after h1 dead (GEMM2 done)
    u16* xa = (u16*)slot2;
    u16* g2 = (u16*)slot2;   // after xa dead (GEMM1 done)
    u16* g3 = (u16*)slot2;   // after g2 dead (agg2 done)

    const int nb_nodes = (N + 255) / 256;
    const int nb_pairs = ((E / 2) + 255) / 256;

    // ---- graph prep (parallel scan) ----
    k_zero_int<<<nb_nodes, 256, 0, stream>>>(cnt_cur, N);
    k_count<<<nb_pairs, 256, 0, stream>>>(ei, E, cnt_cur);
    k_scan_a<<<SCAN_B, 1024, 0, stream>>>(cnt_cur, row_ptr, bsum, dis, N);
    k_scan_b<<<1, 128, 0, stream>>>(bsum, row_ptr, SCAN_B, N, E);
    k_scan_c<<<SCAN_B, 1024, 0, stream>>>(row_ptr, bsum, cnt_cur, N);
    k_scatter<<<nb_pairs, 256, 0, stream>>>(ei, E, dis, cnt_cur, edat);

    // ---- weight transpose+split (one launch), x -> bf16 ----
    k_prep_w_all<<<640, 256, 0, stream>>>(W1, W2, W3, wt1h, wt1l, wt2h, wt2l, wt3h, wt3l);
    const long n8 = (long)N * 128 / 8;
    k_x2bf<<<(int)((n8 + 255) / 256), 256, 0, stream>>>(x, xb, n8);

    const int agg_blocks = (N + 3) / 4;
    const int m_blocks = M_PAD / 256;  // 391

    // ---- layer 1: xa = A*xb (D=128) ; h1 = relu(xa@W1 + b1) ----
    k_agg<128, false, false, 1><<<agg_blocks, 256, 0, stream>>>(
        xb, row_ptr, edat, dis, nullptr, nullptr, xa);
    k_gemm2p<true, true><<<dim3(2, m_blocks), 512, 0, stream>>>(
        xa, wt1h, wt1l, b1, h1, N, 256, 128);

    // ---- layer 2: g2 = h1@W2 ; h2 = relu(A*g2 + b2) ----
    k_gemm2p<false, false><<<dim3(2, m_blocks), 512, 0, stream>>>(
        h1, wt2h, wt2l, nullptr, g2, N, 256, 256);
    k_agg<256, true, true, 1><<<agg_blocks, 256, 0, stream>>>(
        g2, row_ptr, edat, dis, b2, nullptr, h2);

    // ---- layer 3: g3 = h2@W3 ; out = A*g3 + b3 [fp32 out] ----
    k_gemm2p<false, false><<<dim3(1, m_blocks), 512, 0, stream>>>(
        h2, wt3h, wt3l, nullptr, g3, N, 128, 256);
    k_agg<128, true, false, 0><<<agg_blocks, 256, 0, stream>>>(
        g3, row_ptr, edat, dis, b3, out, nullptr);
}